// Round 9
// baseline (326.700 us; speedup 1.0000x reference)
//
#include <hip/hip_runtime.h>
#include <hip/hip_bf16.h>
#include <cmath>

#define NB 32
#define NS 4096
#define NK 1024
#define ND 512
#define WSTRIDE 1536   // ENC2 + DEC
#define NTO 16         // outer K-steps (BK=64 for A; two 32-k B chunks per outer)

using bf16x8 = __attribute__((ext_vector_type(8))) __bf16;
using u16x8  = __attribute__((ext_vector_type(8))) unsigned short;
using f32x4  = __attribute__((ext_vector_type(4))) float;
typedef unsigned short u16;

__device__ inline u16 f2b(float x) {
    __hip_bfloat16 h = __float2bfloat16(x);
    u16 u; __builtin_memcpy(&u, &h, 2); return u;
}

__device__ inline float fast_tanh(float x) {
    float xc = fminf(fmaxf(x, -10.f), 10.f);
    float e = __expf(2.f * xc);
    return (e - 1.f) / (e + 1.f);
}

// ---------------------------------------------------------------------------
// Kernel 0: pack Wc = W_attn[:, 512:] -> bf16, pre-permuted so a LINEAR wave
// copy (global_load_lds) yields the bank-conflict-free LDS image.
// LDS image (64B rows): element (R, k=ks*32+S*8+j) at granule S^((R>>1)&3)
// of row R => 8-lane read cohorts cover all 32 banks (conflict-free b128).
__global__ void pack_wc_kernel(const float* __restrict__ W, u16* __restrict__ wcb) {
    int idx = blockIdx.x * 256 + threadIdx.x;   // 512*1024 elements
    int R = idx >> 10, k = idx & 1023;
    float val = W[(size_t)R * WSTRIDE + ND + k];
    int ks = k >> 5, S = (k >> 3) & 3, j = k & 7;
    int g = (R << 2) + (S ^ ((R >> 1) & 3));    // granule 0..2047 (bijective)
    wcb[(ks << 14) + (g << 3) + j] = f2b(val);
}

// ---------------------------------------------------------------------------
// Kernel 1: h_proj[b][d] = bias[d] + sum_k hidden[b][k] * W_attn[d][k]  (f32 exact)
__global__ void hproj_kernel(const float* __restrict__ hidden, const float* __restrict__ W,
                             const float* __restrict__ bias, float* __restrict__ hp) {
    int b = blockIdx.x, d = threadIdx.x;   // 512 threads
    __shared__ float sh[ND];
    sh[d] = hidden[b * ND + d];
    __syncthreads();
    const float4* wr = (const float4*)(W + (size_t)d * WSTRIDE);
    float acc = bias[d];
#pragma unroll 8
    for (int k = 0; k < ND / 4; k++) {
        float4 w4 = wr[k];
        acc += w4.x * sh[4 * k] + w4.y * sh[4 * k + 1] + w4.z * sh[4 * k + 2] + w4.w * sh[4 * k + 3];
    }
    hp[b * ND + d] = acc;
}

// ---------------------------------------------------------------------------
// Kernel 2: fused c_proj GEMM (bf16 MFMA) + tanh + dot-v -> scores
// Block tile 64x512, 512 threads / 8 waves as 1M x 8N -> wave tile 64x64
// (acc[4][4]=64 regs). Block-wide LDS reads per K-sub: A 32 + B 32 b128
// (was 16+64 with 2Mx4N) -> -20% on the binding LDS-read floor.
// A staged BK=64 (32B contiguous/thread), granule XOR q^(row&7) on 128B rows.
// B staged BK=32 via global_load_lds from pre-swizzled pack (64B rows).
// Counted-vmcnt pipeline; every consumed buffer is drained by vmcnt(2)
// BEFORE the barrier preceding its consumption (cross-wave sound); vmcnt
// never drained to 0 inside the loop (A prefetch always in flight).
__global__ __launch_bounds__(512, 4)
void fused_scores_kernel(const float* __restrict__ ctx, const u16* __restrict__ wcb,
                         const float* __restrict__ hp, const float* __restrict__ vvec,
                         float* __restrict__ scores) {
    __shared__ __align__(16) char lA[2][64 * 128];   // 2 x 8 KB (BK=64 bf16)
    __shared__ __align__(16) char lB[2][512 * 64];   // 2 x 32 KB (BK=32 bf16)
    // total 80 KiB exactly; epilogue scratch aliases lA.

    const int tid = threadIdx.x;
    const int blk = blockIdx.x;             // 2048 blocks
    const int b  = blk >> 6;                // 64 M-tiles per batch
    const int s0 = (blk & 63) << 6;

    const int lane = tid & 63, wid = tid >> 6;
    const int l15 = lane & 15, l4 = lane >> 4;

    // A staging: thread -> row = tid>>3 (0..63), q = tid&7; loads 32B (2 float4,
    // k = q*8..q*8+7) -> one swizzled 16B granule in a 128B LDS row.
    const int srow = tid >> 3, q = tid & 7;
    const float4* asrc = (const float4*)(ctx + (size_t)b * NS * NK + (size_t)(s0 + srow) * NK);
    const int awbyte = (srow << 7) + ((q ^ (srow & 7)) << 4);

    // fragment LDS byte offsets (loop-invariant)
    int aoff[4], boff[4];
#pragma unroll
    for (int r = 0; r < 4; r++) {
        int row = (r << 4) + l15;                         // block M rows 0..63
        aoff[r] = (row << 7) + ((l4 ^ (row & 7)) << 4);   // ks2=1 -> ^64
    }
#pragma unroll
    for (int c = 0; c < 4; c++) {
        int row = (wid << 6) + (c << 4) + l15;            // wave owns 64 d-cols
        boff[c] = (row << 6) + ((l4 ^ ((row >> 1) & 3)) << 4);
    }

    f32x4 acc[4][4];
    f32x4 zero = {0.f, 0.f, 0.f, 0.f};
#pragma unroll
    for (int r = 0; r < 4; r++)
#pragma unroll
        for (int c = 0; c < 4; c++) acc[r][c] = zero;

    const char* wcb_bytes = (const char*)wcb;
    float4 va0, va1;

#define STAGE_B_DMA(chunk, buf)                                                      \
    _Pragma("unroll")                                                                \
    for (int i = 0; i < 4; i++) {                                                    \
        const char* src = wcb_bytes + ((size_t)(chunk) << 15)                        \
                          + (((((wid << 2) + i) << 6) + lane) << 4);                 \
        __builtin_amdgcn_global_load_lds(                                            \
            (const __attribute__((address_space(1))) void*)src,                      \
            (__attribute__((address_space(3))) void*)(&lB[buf][((wid << 2) + i) << 10]), \
            16, 0, 0);                                                               \
    }

#define LOAD_A_REGS(tile)                                                            \
    {                                                                                \
        va0 = asrc[((tile) << 4) + (q << 1)];                                        \
        va1 = asrc[((tile) << 4) + (q << 1) + 1];                                    \
    }

#define CVT_WRITE_A(buf)                                                             \
    {                                                                                \
        u16x8 a8;                                                                    \
        a8[0] = f2b(va0.x); a8[1] = f2b(va0.y); a8[2] = f2b(va0.z); a8[3] = f2b(va0.w); \
        a8[4] = f2b(va1.x); a8[5] = f2b(va1.y); a8[6] = f2b(va1.z); a8[7] = f2b(va1.w); \
        *(u16x8*)(&lA[buf][awbyte]) = a8;                                            \
    }

#define MFMA_CLUSTER(abuf, axor, bbuf)                                               \
    {                                                                                \
        bf16x8 af[4], bfr[4];                                                        \
        _Pragma("unroll")                                                            \
        for (int r = 0; r < 4; r++) af[r] = *(const bf16x8*)(&lA[abuf][aoff[r] ^ (axor)]); \
        _Pragma("unroll")                                                            \
        for (int c = 0; c < 4; c++) bfr[c] = *(const bf16x8*)(&lB[bbuf][boff[c]]);   \
        __builtin_amdgcn_s_setprio(1);                                               \
        _Pragma("unroll")                                                            \
        for (int r = 0; r < 4; r++)                                                  \
            _Pragma("unroll")                                                        \
            for (int c = 0; c < 4; c++)                                              \
                acc[r][c] = __builtin_amdgcn_mfma_f32_16x16x32_bf16(                 \
                    af[r], bfr[c], acc[r][c], 0, 0, 0);                              \
        __builtin_amdgcn_s_setprio(0);                                               \
    }

    // ---- prologue: stage B chunk 0 + A tile 0, prefetch A(1) regs ----
    STAGE_B_DMA(0, 0);
    LOAD_A_REGS(0);
    asm volatile("s_waitcnt vmcnt(0)" ::: "memory");
    CVT_WRITE_A(0);
    LOAD_A_REGS(1);
    asm volatile("s_waitcnt lgkmcnt(0)" ::: "memory");
    __builtin_amdgcn_s_barrier();
    __builtin_amdgcn_sched_barrier(0);

    // ---- main loop: invariant at sub0 entry = exactly A(t+1)x2 outstanding,
    //      and lB[0] (chunk u0) already drained before the preceding barrier.
#pragma unroll 2
    for (int t = 0; t < NTO; t++) {
        const int curA = t & 1, nxtA = curA ^ 1;
        const int u0 = t << 1;

        // ===== sub0: A-half ks2=0 x B chunk u0 (lB[0]) =====
        {
            const int cB = (u0 + 1 < 32) ? u0 + 1 : 31;
            STAGE_B_DMA(cB, 1);                                // +4 -> 6 outstanding
            asm volatile("s_waitcnt vmcnt(4)" ::: "memory");   // A(t+1) regs landed
            CVT_WRITE_A(nxtA);
            const int tA = (t + 2 < NTO) ? t + 2 : NTO - 1;
            LOAD_A_REGS(tA);                                   // A(t+2) in flight
            MFMA_CLUSTER(curA, 0, 0);
            asm volatile("s_waitcnt vmcnt(2) lgkmcnt(0)" ::: "memory"); // drain B(u0+1)+A ds_write
            __builtin_amdgcn_s_barrier();
            __builtin_amdgcn_sched_barrier(0);
        }
        // ===== sub1: A-half ks2=1 x B chunk u0+1 (lB[1]) =====
        {
            const int cB = (u0 + 2 < 32) ? u0 + 2 : 31;
            STAGE_B_DMA(cB, 0);                                // +4 -> 6 outstanding
            MFMA_CLUSTER(curA, 64, 1);
            asm volatile("s_waitcnt vmcnt(2) lgkmcnt(0)" ::: "memory"); // drain B(u0+2) pre-barrier
            __builtin_amdgcn_s_barrier();
            __builtin_amdgcn_sched_barrier(0);
        }
    }

    // --- epilogue: tanh(c_proj + h_proj) . v , reduce over d ---
    // C/D: col = lane&15 (d), row = l4*4 + i (s within frag)
    const float* hpb = hp + b * ND;
    float part[4][4];
#pragma unroll
    for (int r = 0; r < 4; r++)
#pragma unroll
        for (int i = 0; i < 4; i++) part[r][i] = 0.f;

#pragma unroll
    for (int c = 0; c < 4; c++) {
        int d = (wid << 6) + (c << 4) + l15;
        float hpv = hpb[d], vv = vvec[d];
#pragma unroll
        for (int r = 0; r < 4; r++)
#pragma unroll
            for (int i = 0; i < 4; i++)
                part[r][i] += fast_tanh(acc[r][c][i] + hpv) * vv;
    }

    float* sc = (float*)lA;   // 8 x 64 floats, aliases lA (all lA reads done)
#pragma unroll
    for (int r = 0; r < 4; r++) {
#pragma unroll
        for (int i = 0; i < 4; i++) {
            float p = part[r][i];
            p += __shfl_xor(p, 1); p += __shfl_xor(p, 2);
            p += __shfl_xor(p, 4); p += __shfl_xor(p, 8);
            if (l15 == 0) sc[(wid << 6) + (r << 4) + (l4 << 2) + i] = p;
        }
    }
    __syncthreads();
    if (tid < 64) {
        float s = 0.f;
#pragma unroll
        for (int w = 0; w < 8; w++) s += sc[(w << 6) + tid];
        scores[(size_t)b * NS + s0 + tid] = s;
    }
}

// ---------------------------------------------------------------------------
// Kernel 3: masked softmax over S per batch row, f32 output
__global__ void softmax_kernel(const float* __restrict__ scores, const int* __restrict__ mask,
                               float* __restrict__ out) {
    int b = blockIdx.x, tid = threadIdx.x;   // 256 threads, 16 elems each
    __shared__ float red[256];
    float loc[16];
    float mx = -INFINITY;
#pragma unroll
    for (int i = 0; i < 16; i++) {
        int idx = i * 256 + tid;
        float s = scores[b * NS + idx];
        if (mask[b * NS + idx] == 0) s = -INFINITY;
        loc[i] = s;
        mx = fmaxf(mx, s);
    }
    red[tid] = mx; __syncthreads();
    for (int off = 128; off; off >>= 1) { if (tid < off) red[tid] = fmaxf(red[tid], red[tid + off]); __syncthreads(); }
    mx = red[0]; __syncthreads();
    float sum = 0.f;
#pragma unroll
    for (int i = 0; i < 16; i++) { float e = __expf(loc[i] - mx); loc[i] = e; sum += e; }
    red[tid] = sum; __syncthreads();
    for (int off = 128; off; off >>= 1) { if (tid < off) red[tid] += red[tid + off]; __syncthreads(); }
    float inv = 1.f / red[0];
#pragma unroll
    for (int i = 0; i < 16; i++) out[b * NS + i * 256 + tid] = loc[i] * inv;
}

// ---------------------------------------------------------------------------
extern "C" void kernel_launch(void* const* d_in, const int* in_sizes, int n_in,
                              void* d_out, int out_size, void* d_ws, size_t ws_size,
                              hipStream_t stream) {
    const float* hidden  = (const float*)d_in[0];
    const float* context = (const float*)d_in[1];
    const int*   mask    = (const int*)d_in[2];
    const float* W_attn  = (const float*)d_in[3];
    const float* b_attn  = (const float*)d_in[4];
    const float* v       = (const float*)d_in[5];
    float* out           = (float*)d_out;

    char* ws = (char*)d_ws;
    u16*   wcb    = (u16*)ws;                   // 1 MB
    float* hp     = (float*)(ws + (1 << 20));   // 64 KB
    float* scores = (float*)(ws + (1 << 20) + (64 << 10));  // 512 KB

    pack_wc_kernel<<<2048, 256, 0, stream>>>(W_attn, wcb);
    hproj_kernel<<<NB, ND, 0, stream>>>(hidden, W_attn, b_attn, hp);
    fused_scores_kernel<<<NB * 64, 512, 0, stream>>>(context, wcb, hp, v, scores);
    softmax_kernel<<<NB, 256, 0, stream>>>(scores, mask, out);
}

// Round 10
// 269.059 us; speedup vs baseline: 1.2142x; 1.2142x over previous
//
#include <hip/hip_runtime.h>
#include <hip/hip_bf16.h>
#include <cmath>

#define NB 32
#define NS 4096
#define NK 1024
#define ND 512
#define WSTRIDE 1536   // ENC2 + DEC
#define NT 32          // K-steps (BK=32)

using bf16x8 = __attribute__((ext_vector_type(8))) __bf16;
using f32x4  = __attribute__((ext_vector_type(4))) float;
typedef unsigned short u16;

__device__ inline u16 f2b(float x) {
    __hip_bfloat16 h = __float2bfloat16(x);
    u16 u; __builtin_memcpy(&u, &h, 2); return u;
}

__device__ inline float fast_tanh(float x) {
    float xc = fminf(fmaxf(x, -10.f), 10.f);
    float e = __expf(2.f * xc);
    return (e - 1.f) / (e + 1.f);
}

// ---------------------------------------------------------------------------
// Kernel 0: pack Wc = W_attn[:, 512:] -> bf16, pre-permuted so a LINEAR wave
// copy (global_load_lds) yields the bank-conflict-free LDS image.
// LDS image (64B rows): element (R, k=ks*32+S*8+j) at 16B-granule S^((R>>1)&3)
// of row R  =>  linear granule g = R*4 + (S ^ ((R>>1)&3)).
// (empirically conflict-free: SQ_LDS_BANK_CONFLICT = 0 in round 9)
__global__ void pack_wc_kernel(const float* __restrict__ W, u16* __restrict__ wcb) {
    int idx = blockIdx.x * 256 + threadIdx.x;   // 512*1024 elements
    int R = idx >> 10, k = idx & 1023;
    float val = W[(size_t)R * WSTRIDE + ND + k];
    int ks = k >> 5, S = (k >> 3) & 3, j = k & 7;
    int g = (R << 2) + (S ^ ((R >> 1) & 3));    // granule 0..2047 (bijective)
    wcb[(ks << 14) + (g << 3) + j] = f2b(val);
}

// ---------------------------------------------------------------------------
// Kernel 1: h_proj[b][d] = bias[d] + sum_k hidden[b][k] * W_attn[d][k]  (f32 exact)
__global__ void hproj_kernel(const float* __restrict__ hidden, const float* __restrict__ W,
                             const float* __restrict__ bias, float* __restrict__ hp) {
    int b = blockIdx.x, d = threadIdx.x;   // 512 threads
    __shared__ float sh[ND];
    sh[d] = hidden[b * ND + d];
    __syncthreads();
    const float4* wr = (const float4*)(W + (size_t)d * WSTRIDE);
    float acc = bias[d];
#pragma unroll 8
    for (int k = 0; k < ND / 4; k++) {
        float4 w4 = wr[k];
        acc += w4.x * sh[4 * k] + w4.y * sh[4 * k + 1] + w4.z * sh[4 * k + 2] + w4.w * sh[4 * k + 3];
    }
    hp[b * ND + d] = acc;
}

// ---------------------------------------------------------------------------
// Kernel 2: fused c_proj GEMM (bf16 MFMA) + tanh + dot-v -> scores
// Block tile 128x512, BK=32, 1024 threads / 16 waves as 4M x 4N ->
// wave tile 32x128 (acc[2][8]=64 VGPR) — identical per-wave shape to the
// round-8 winner; geometry change only: BM 64->128 halves the per-block
// B re-staging (total B L2->LDS DMA 2 GiB -> 1 GiB).
// LDS exactly 80 KiB: lA 2x8K (128 rows x 32k bf16) + lB 2x32K.
// Counted-vmcnt single-sub loop: per wave entry = A(t+1)x1 outstanding;
// +2 B-DMA -> vmcnt(2) drains A; +A(t+2) -> MFMA -> vmcnt(1)+lgkmcnt(0)
// drains B before the one barrier per step (cross-wave sound). Never 0.
__global__ __launch_bounds__(1024, 4)
void fused_scores_kernel(const float* __restrict__ ctx, const u16* __restrict__ wcb,
                         const float* __restrict__ hp, const float* __restrict__ vvec,
                         float* __restrict__ scores) {
    __shared__ __align__(16) char lA[2][128 * 64];   // 2 x 8 KB (BK=32 bf16)
    __shared__ __align__(16) char lB[2][512 * 64];   // 2 x 32 KB (BK=32 bf16)
    // total 80 KiB exactly; epilogue scratch aliases lA.

    const int tid = threadIdx.x;
    const int blk = blockIdx.x;             // 1024 blocks
    const int b  = blk >> 5;                // 32 M-tiles per batch
    const int s0 = (blk & 31) << 7;

    const int lane = tid & 63, wid = tid >> 6;      // wid 0..15
    const int l15 = lane & 15, l4 = lane >> 4;
    const int wm = wid >> 2, wn = wid & 3;          // 4M x 4N

    // A staging: thread -> row = tid>>3 (0..127), q = tid&7; one float4
    // (k = q*4..q*4+3) -> 4 bf16 = 8B LDS write at the swizzled granule-half.
    const int srow = tid >> 3, q = tid & 7;
    const float4* asrc = (const float4*)(ctx + (size_t)b * NS * NK + (size_t)(s0 + srow) * NK);
    const int awbyte = (srow << 6) + ((((q >> 1) ^ ((srow >> 1) & 3))) << 4) + ((q & 1) << 3);

    // fragment LDS byte offsets (loop-invariant); same swizzle family for A & B
    int aoff[2], boff[8];
#pragma unroll
    for (int r = 0; r < 2; r++) {
        int row = (wm << 5) + (r << 4) + l15;             // block M rows 0..127
        aoff[r] = (row << 6) + ((l4 ^ ((row >> 1) & 3)) << 4);
    }
#pragma unroll
    for (int c = 0; c < 8; c++) {
        int row = (wn << 7) + (c << 4) + l15;             // wave owns 128 d-cols
        boff[c] = (row << 6) + ((l4 ^ ((row >> 1) & 3)) << 4);
    }

    f32x4 acc[2][8];
    f32x4 zero = {0.f, 0.f, 0.f, 0.f};
#pragma unroll
    for (int r = 0; r < 2; r++)
#pragma unroll
        for (int c = 0; c < 8; c++) acc[r][c] = zero;

    const char* wcb_bytes = (const char*)wcb;
    float4 va;

#define STAGE_B_DMA(chunk, buf)                                                      \
    _Pragma("unroll")                                                                \
    for (int i = 0; i < 2; i++) {                                                    \
        const char* src = wcb_bytes + ((size_t)(chunk) << 15)                        \
                          + (((((wid << 1) + i) << 6) + lane) << 4);                 \
        __builtin_amdgcn_global_load_lds(                                            \
            (const __attribute__((address_space(1))) void*)src,                      \
            (__attribute__((address_space(3))) void*)(&lB[buf][((wid << 1) + i) << 10]), \
            16, 0, 0);                                                               \
    }

#define CVT_WRITE_A(buf)                                                             \
    {                                                                                \
        ushort4 a4;                                                                  \
        a4.x = f2b(va.x); a4.y = f2b(va.y); a4.z = f2b(va.z); a4.w = f2b(va.w);      \
        *(ushort4*)(&lA[buf][awbyte]) = a4;                                          \
    }

#define MFMA_CLUSTER(abuf, bbuf)                                                     \
    {                                                                                \
        bf16x8 af[2];                                                                \
        _Pragma("unroll")                                                            \
        for (int r = 0; r < 2; r++) af[r] = *(const bf16x8*)(&lA[abuf][aoff[r]]);    \
        _Pragma("unroll")                                                            \
        for (int ch = 0; ch < 2; ch++) {                                             \
            bf16x8 bfr[4];                                                           \
            _Pragma("unroll")                                                        \
            for (int c = 0; c < 4; c++) bfr[c] = *(const bf16x8*)(&lB[bbuf][boff[ch * 4 + c]]); \
            __builtin_amdgcn_s_setprio(1);                                           \
            _Pragma("unroll")                                                        \
            for (int r = 0; r < 2; r++)                                              \
                _Pragma("unroll")                                                    \
                for (int c = 0; c < 4; c++)                                          \
                    acc[r][ch * 4 + c] = __builtin_amdgcn_mfma_f32_16x16x32_bf16(    \
                        af[r], bfr[c], acc[r][ch * 4 + c], 0, 0, 0);                 \
            __builtin_amdgcn_s_setprio(0);                                           \
        }                                                                            \
    }

    // ---- prologue: stage B chunk 0 + A tile 0, prefetch A(1) regs ----
    STAGE_B_DMA(0, 0);
    va = asrc[q];
    asm volatile("s_waitcnt vmcnt(0)" ::: "memory");
    CVT_WRITE_A(0);
    va = asrc[8 + q];                  // A(1) in flight
    asm volatile("s_waitcnt lgkmcnt(0)" ::: "memory");
    __builtin_amdgcn_s_barrier();
    __builtin_amdgcn_sched_barrier(0);

    // ---- main loop: one 32-k step per iter, one barrier per iter ----
#pragma unroll 2
    for (int t = 0; t < NT; t++) {
        const int cur = t & 1, nxt = cur ^ 1;
        const int cB = (t + 1 < NT) ? t + 1 : NT - 1;   // clamp keeps counts uniform
        const int tA = (t + 2 < NT) ? t + 2 : NT - 1;

        STAGE_B_DMA(cB, nxt);                              // +2 -> 3 outstanding
        asm volatile("s_waitcnt vmcnt(2)" ::: "memory");   // A(t+1) reg landed
        CVT_WRITE_A(nxt);
        va = asrc[(tA << 3) + q];                          // A(t+2) in flight
        MFMA_CLUSTER(cur, cur);
        asm volatile("s_waitcnt vmcnt(1) lgkmcnt(0)" ::: "memory"); // drain B(t+1), keep A
        __builtin_amdgcn_s_barrier();
        __builtin_amdgcn_sched_barrier(0);
    }

    // --- epilogue: tanh(c_proj + h_proj) . v , reduce over d ---
    // C/D: col = lane&15 (d), row = l4*4 + i (s within frag)
    const float* hpb = hp + b * ND;
    float part[2][4];
#pragma unroll
    for (int r = 0; r < 2; r++)
#pragma unroll
        for (int i = 0; i < 4; i++) part[r][i] = 0.f;

#pragma unroll
    for (int c = 0; c < 8; c++) {
        int d = (wn << 7) + (c << 4) + l15;
        float hpv = hpb[d], vv = vvec[d];
#pragma unroll
        for (int r = 0; r < 2; r++)
#pragma unroll
            for (int i = 0; i < 4; i++)
                part[r][i] += fast_tanh(acc[r][c][i] + hpv) * vv;
    }

    float* sc = (float*)lA;   // 4 x 128 floats = 2 KB, aliases lA (reads done)
#pragma unroll
    for (int r = 0; r < 2; r++) {
#pragma unroll
        for (int i = 0; i < 4; i++) {
            float p = part[r][i];
            p += __shfl_xor(p, 1); p += __shfl_xor(p, 2);
            p += __shfl_xor(p, 4); p += __shfl_xor(p, 8);
            if (l15 == 0) sc[(wn << 7) + (wm << 5) + (r << 4) + (l4 << 2) + i] = p;
        }
    }
    __syncthreads();
    if (tid < 128) {
        float s = sc[tid] + sc[128 + tid] + sc[256 + tid] + sc[384 + tid];
        scores[(size_t)b * NS + s0 + tid] = s;
    }
}

// ---------------------------------------------------------------------------
// Kernel 3: masked softmax over S per batch row, f32 output
__global__ void softmax_kernel(const float* __restrict__ scores, const int* __restrict__ mask,
                               float* __restrict__ out) {
    int b = blockIdx.x, tid = threadIdx.x;   // 256 threads, 16 elems each
    __shared__ float red[256];
    float loc[16];
    float mx = -INFINITY;
#pragma unroll
    for (int i = 0; i < 16; i++) {
        int idx = i * 256 + tid;
        float s = scores[b * NS + idx];
        if (mask[b * NS + idx] == 0) s = -INFINITY;
        loc[i] = s;
        mx = fmaxf(mx, s);
    }
    red[tid] = mx; __syncthreads();
    for (int off = 128; off; off >>= 1) { if (tid < off) red[tid] = fmaxf(red[tid], red[tid + off]); __syncthreads(); }
    mx = red[0]; __syncthreads();
    float sum = 0.f;
#pragma unroll
    for (int i = 0; i < 16; i++) { float e = __expf(loc[i] - mx); loc[i] = e; sum += e; }
    red[tid] = sum; __syncthreads();
    for (int off = 128; off; off >>= 1) { if (tid < off) red[tid] += red[tid + off]; __syncthreads(); }
    float inv = 1.f / red[0];
#pragma unroll
    for (int i = 0; i < 16; i++) out[b * NS + i * 256 + tid] = loc[i] * inv;
}

// ---------------------------------------------------------------------------
extern "C" void kernel_launch(void* const* d_in, const int* in_sizes, int n_in,
                              void* d_out, int out_size, void* d_ws, size_t ws_size,
                              hipStream_t stream) {
    const float* hidden  = (const float*)d_in[0];
    const float* context = (const float*)d_in[1];
    const int*   mask    = (const int*)d_in[2];
    const float* W_attn  = (const float*)d_in[3];
    const float* b_attn  = (const float*)d_in[4];
    const float* v       = (const float*)d_in[5];
    float* out           = (float*)d_out;

    char* ws = (char*)d_ws;
    u16*   wcb    = (u16*)ws;                   // 1 MB
    float* hp     = (float*)(ws + (1 << 20));   // 64 KB
    float* scores = (float*)(ws + (1 << 20) + (64 << 10));  // 512 KB

    pack_wc_kernel<<<2048, 256, 0, stream>>>(W_attn, wcb);
    hproj_kernel<<<NB, ND, 0, stream>>>(hidden, W_attn, b_attn, hp);
    fused_scores_kernel<<<NB * 32, 1024, 0, stream>>>(context, wcb, hp, v, scores);
    softmax_kernel<<<NB, 256, 0, stream>>>(scores, mask, out);
}